// Round 1
// baseline (144.943 us; speedup 1.0000x reference)
//
#include <hip/hip_runtime.h>

#define GN 512
#define HH 32
#define DD 64

typedef float v4f __attribute__((ext_vector_type(4)));
typedef unsigned int v4u __attribute__((ext_vector_type(4)));
typedef __bf16 v8bf __attribute__((ext_vector_type(8)));

__device__ __forceinline__ unsigned int f2bf(float f) {
  unsigned int u = __builtin_bit_cast(unsigned int, f);
  return (u + 0x7fffu + ((u >> 16) & 1u)) >> 16;
}
__device__ __forceinline__ unsigned int pack2(float a, float b) {
  return f2bf(a) | (f2bf(b) << 16);
}

// ---------------- Stage 1: keys/queries projections -------------------------
// kk[b,n,h] = receiver[b,n,:] @ w_k[:,h] + bias[h]
// q [b,n,h] = attendant[b,n,:] @ w_q[:,h]
__global__ __launch_bounds__(256) void kq_kernel(const float* __restrict__ rec,
                                                 const float* __restrict__ att,
                                                 const float* __restrict__ wq,
                                                 const float* __restrict__ wk,
                                                 const float* __restrict__ bias,
                                                 float* __restrict__ kkbuf,
                                                 float* __restrict__ qbuf) {
  __shared__ float rr[512], ra[512];
  int tid = threadIdx.x;
  size_t base = (size_t)blockIdx.x * 8;  // 8 rows of the 16384 (b,n) rows
  const float* gr = rec + base * DD;
  const float* ga = att + base * DD;
  rr[tid] = gr[tid]; rr[tid + 256] = gr[tid + 256];
  ra[tid] = ga[tid]; ra[tid + 256] = ga[tid + 256];
  __syncthreads();
  int r = tid >> 5, h = tid & 31;
  float sk = bias[h], sq = 0.f;
  const float* rrow = &rr[r * DD];
  const float* arow = &ra[r * DD];
#pragma unroll 8
  for (int d = 0; d < DD; ++d) {
    sk += rrow[d] * wk[d * HH + h];
    sq += arow[d] * wq[d * HH + h];
  }
  kkbuf[(base + r) * HH + h] = sk;
  qbuf[(base + r) * HH + h] = sq;
}

// ---------------- Stage 2: adj -> adjT (bf16) -------------------------------
__global__ __launch_bounds__(256) void transpose_kernel(const float* __restrict__ adj,
                                                        unsigned short* __restrict__ adjT) {
  __shared__ float t[64][65];
  int b = blockIdx.z;
  int c0 = blockIdx.x * 64, r0 = blockIdx.y * 64;
  const float* ab = adj + (size_t)b * GN * GN;
  unsigned short* ob = adjT + (size_t)b * GN * GN;
  int tid = threadIdx.x;
#pragma unroll
  for (int k = 0; k < 4; ++k) {
    int v = tid + k * 256;
    int row = v >> 4, seg = v & 15;
    v4f f = *(const v4f*)(ab + (size_t)(r0 + row) * GN + c0 + seg * 4);
    t[row][seg * 4 + 0] = f[0];
    t[row][seg * 4 + 1] = f[1];
    t[row][seg * 4 + 2] = f[2];
    t[row][seg * 4 + 3] = f[3];
  }
  __syncthreads();
  int c = tid >> 2;            // output row = original column
  int rs = (tid & 3) * 16;     // 16 output cols = original rows
  v4u p0, p1;
#pragma unroll
  for (int j = 0; j < 4; ++j) {
    p0[j] = pack2(t[rs + 2 * j][c], t[rs + 2 * j + 1][c]);
    p1[j] = pack2(t[rs + 8 + 2 * j][c], t[rs + 9 + 2 * j][c]);
  }
  unsigned short* dst = ob + (size_t)(c0 + c) * GN + r0 + rs;
  *(v4u*)dst = p0;
  *(v4u*)(dst + 8) = p1;
}

// ---------------- Stage 3: e-scores, stored transposed ----------------------
// Et[b][m][n] = sum_h a[h] * tanh(q[b,m,h] + kk[b,n,h])       (bias folded in kk)
__global__ __launch_bounds__(256) void escore_kernel(const float* __restrict__ kk,
                                                     const float* __restrict__ q,
                                                     const float* __restrict__ avec,
                                                     unsigned short* __restrict__ Et) {
  __shared__ float kl[64][36], ql[64][36];
  int b = blockIdx.z;
  int n0 = blockIdx.x * 64, m0 = blockIdx.y * 64;
  const float* kb = kk + ((size_t)b * GN + n0) * HH;
  const float* qb = q + ((size_t)b * GN + m0) * HH;
  int tid = threadIdx.x;
#pragma unroll
  for (int k = 0; k < 2; ++k) {
    int v = tid + k * 256;
    int row = v >> 3, seg = v & 7;
    *(v4f*)&kl[row][seg * 4] = *(const v4f*)(kb + row * HH + seg * 4);
    *(v4f*)&ql[row][seg * 4] = *(const v4f*)(qb + row * HH + seg * 4);
  }
  __syncthreads();
  float areg[HH], qreg[HH];
  int m = tid >> 2, ng = tid & 3;
#pragma unroll
  for (int h4 = 0; h4 < 8; ++h4) {
    v4f av = *(const v4f*)(avec + h4 * 4);
    v4f qv = *(const v4f*)&ql[m][h4 * 4];
#pragma unroll
    for (int e = 0; e < 4; ++e) {
      areg[h4 * 4 + e] = av[e];
      qreg[h4 * 4 + e] = qv[e];
    }
  }
  unsigned short* dst = Et + ((size_t)b * GN + m0 + m) * GN + n0;
#pragma unroll 2
  for (int jj = 0; jj < 16; ++jj) {
    int n = jj * 4 + ng;  // lane-group-major: conflict-free kl reads
    float acc = 0.f;
#pragma unroll
    for (int h4 = 0; h4 < 8; ++h4) {
      v4f kv = *(const v4f*)&kl[n][h4 * 4];
#pragma unroll
      for (int e = 0; e < 4; ++e) {
        float x = qreg[h4 * 4 + e] + kv[e];
        float ex = __expf(2.0f * x);                       // v_exp_f32
        float th = 1.0f - 2.0f * __builtin_amdgcn_rcpf(ex + 1.0f);
        acc += areg[h4 * 4 + e] * th;
      }
    }
    dst[n] = (unsigned short)f2bf(acc);
  }
}

// ---------------- Stage 4/5: batched GEMM, C = A * Bt^T ---------------------
// A row-major [512][512] (f32 or bf16), Bt row-major [col][k] bf16.
// 128x128 tile, BK=32, 4 waves, 4x4 fragments of mfma_f32_16x16x32_bf16.
template <bool AFLOAT, bool OUTF32>
__global__ __launch_bounds__(256) void gemm_bt(const void* __restrict__ Av,
                                               const unsigned short* __restrict__ Bt,
                                               void* __restrict__ Cv) {
  __shared__ unsigned short At[128 * 40];  // +8 pad: row stride 80B -> 2-way conflicts only
  __shared__ unsigned short Bs[128 * 40];
  int b = blockIdx.z;
  int row0 = blockIdx.y * 128, col0 = blockIdx.x * 128;
  int tid = threadIdx.x;
  int lane = tid & 63, wave = tid >> 6;
  int wr = wave >> 1, wc = wave & 1;
  int srow = tid >> 1, shalf = tid & 1;

  v4f acc[4][4];
#pragma unroll
  for (int i = 0; i < 4; ++i)
#pragma unroll
    for (int j = 0; j < 4; ++j) acc[i][j] = (v4f){0.f, 0.f, 0.f, 0.f};

  const float* Af = (const float*)Av + (size_t)b * GN * GN + (size_t)(row0 + srow) * GN;
  const unsigned short* Ah =
      (const unsigned short*)Av + (size_t)b * GN * GN + (size_t)(row0 + srow) * GN;
  const unsigned short* Bp = Bt + (size_t)b * GN * GN + (size_t)(col0 + srow) * GN;

  for (int kt = 0; kt < GN / 32; ++kt) {
    int kb = kt * 32 + shalf * 16;
    v4u a0, a1;
    if constexpr (AFLOAT) {
      v4f f0 = *(const v4f*)(Af + kb);
      v4f f1 = *(const v4f*)(Af + kb + 4);
      v4f f2 = *(const v4f*)(Af + kb + 8);
      v4f f3 = *(const v4f*)(Af + kb + 12);
      a0[0] = pack2(f0[0], f0[1]); a0[1] = pack2(f0[2], f0[3]);
      a0[2] = pack2(f1[0], f1[1]); a0[3] = pack2(f1[2], f1[3]);
      a1[0] = pack2(f2[0], f2[1]); a1[1] = pack2(f2[2], f2[3]);
      a1[2] = pack2(f3[0], f3[1]); a1[3] = pack2(f3[2], f3[3]);
    } else {
      a0 = *(const v4u*)(Ah + kb);
      a1 = *(const v4u*)(Ah + kb + 8);
    }
    v4u bb0 = *(const v4u*)(Bp + kb);
    v4u bb1 = *(const v4u*)(Bp + kb + 8);
    __syncthreads();  // previous iteration's MFMA reads done
    {
      v4u* ad = (v4u*)&At[srow * 40 + shalf * 16];
      ad[0] = a0; ad[1] = a1;
      v4u* bd = (v4u*)&Bs[srow * 40 + shalf * 16];
      bd[0] = bb0; bd[1] = bb1;
    }
    __syncthreads();
    int ko = (lane >> 4) * 8;
    int lr = lane & 15;
    v8bf af[4], bf[4];
#pragma unroll
    for (int i = 0; i < 4; ++i)
      af[i] = *(const v8bf*)&At[(wr * 64 + i * 16 + lr) * 40 + ko];
#pragma unroll
    for (int j = 0; j < 4; ++j)
      bf[j] = *(const v8bf*)&Bs[(wc * 64 + j * 16 + lr) * 40 + ko];
#pragma unroll
    for (int i = 0; i < 4; ++i)
#pragma unroll
      for (int j = 0; j < 4; ++j)
        acc[i][j] = __builtin_amdgcn_mfma_f32_16x16x32_bf16(af[i], bf[j], acc[i][j], 0, 0, 0);
  }

  int lc = lane & 15;
  int lrow4 = (lane >> 4) * 4;
#pragma unroll
  for (int i = 0; i < 4; ++i) {
#pragma unroll
    for (int j = 0; j < 4; ++j) {
      int gr = row0 + wr * 64 + i * 16 + lrow4;
      int gc = col0 + wc * 64 + j * 16 + lc;
#pragma unroll
      for (int e = 0; e < 4; ++e) {
        float v = acc[i][j][e];
        if constexpr (OUTF32)
          ((float*)Cv)[(size_t)b * GN * GN + (size_t)(gr + e) * GN + gc] = v;
        else
          ((unsigned short*)Cv)[(size_t)b * GN * GN + (size_t)(gr + e) * GN + gc] =
              (unsigned short)f2bf(v);
      }
    }
  }
}

// ---------------- launch ----------------------------------------------------
extern "C" void kernel_launch(void* const* d_in, const int* in_sizes, int n_in,
                              void* d_out, int out_size, void* d_ws, size_t ws_size,
                              hipStream_t stream) {
  const float* receiver  = (const float*)d_in[0];
  const float* attendant = (const float*)d_in[1];
  const float* adj       = (const float*)d_in[2];
  const float* wq        = (const float*)d_in[3];
  const float* wk        = (const float*)d_in[4];
  const float* bias      = (const float*)d_in[5];
  const float* avec      = (const float*)d_in[6];
  float* out = (float*)d_out;

  char* ws = (char*)d_ws;
  float* kkbuf          = (float*)(ws);                          // 2 MiB
  float* qbuf           = (float*)(ws + (2u << 20));             // 2 MiB
  unsigned short* Et    = (unsigned short*)(ws + (4u << 20));    // 16 MiB
  unsigned short* adjT  = (unsigned short*)(ws + (20u << 20));   // 16 MiB
  unsigned short* Tbuf  = (unsigned short*)(ws + (36u << 20));   // 16 MiB

  kq_kernel<<<dim3(2048), dim3(256), 0, stream>>>(receiver, attendant, wq, wk, bias,
                                                  kkbuf, qbuf);
  transpose_kernel<<<dim3(8, 8, 32), dim3(256), 0, stream>>>(adj, adjT);
  escore_kernel<<<dim3(8, 8, 32), dim3(256), 0, stream>>>(kkbuf, qbuf, avec, Et);
  // T = adj (f32) @ Et^T  -> bf16
  gemm_bt<true, false><<<dim3(4, 4, 32), dim3(256), 0, stream>>>(adj, Et, Tbuf);
  // out = T (bf16) @ adjT^T -> f32
  gemm_bt<false, true><<<dim3(4, 4, 32), dim3(256), 0, stream>>>(Tbuf, adjT, out);
}

// Round 2
// 109.219 us; speedup vs baseline: 1.3271x; 1.3271x over previous
//
#include <hip/hip_runtime.h>

#define GN 512
#define HH 32
#define DD 64

typedef float v4f __attribute__((ext_vector_type(4)));
typedef unsigned int v4u __attribute__((ext_vector_type(4)));
typedef __bf16 v8bf __attribute__((ext_vector_type(8)));

__device__ __forceinline__ unsigned int f2bf(float f) {
  unsigned int u = __builtin_bit_cast(unsigned int, f);
  return (u + 0x7fffu + ((u >> 16) & 1u)) >> 16;
}
__device__ __forceinline__ unsigned int pack2(float a, float b) {
  return f2bf(a) | (f2bf(b) << 16);
}

// ---------------- Stage 1: projections -> exp space -------------------------
// ek[b,n,h] = exp(2*(receiver@w_k + bias))   eq[b,n,h] = exp(2*(attendant@w_q))
__global__ __launch_bounds__(256) void kq_kernel(const float* __restrict__ rec,
                                                 const float* __restrict__ att,
                                                 const float* __restrict__ wq,
                                                 const float* __restrict__ wk,
                                                 const float* __restrict__ bias,
                                                 float* __restrict__ ekbuf,
                                                 float* __restrict__ eqbuf) {
  __shared__ float rr[512], ra[512];
  int tid = threadIdx.x;
  size_t base = (size_t)blockIdx.x * 8;  // 8 rows of the 16384 (b,n) rows
  const float* gr = rec + base * DD;
  const float* ga = att + base * DD;
  rr[tid] = gr[tid]; rr[tid + 256] = gr[tid + 256];
  ra[tid] = ga[tid]; ra[tid + 256] = ga[tid + 256];
  __syncthreads();
  int r = tid >> 5, h = tid & 31;
  float sk = bias[h], sq = 0.f;
  const float* rrow = &rr[r * DD];
  const float* arow = &ra[r * DD];
#pragma unroll 8
  for (int d = 0; d < DD; ++d) {
    sk += rrow[d] * wk[d * HH + h];
    sq += arow[d] * wq[d * HH + h];
  }
  const float C = 2.8853900817779268f;  // 2*log2(e);  exp(2x) = exp2(C*x)
  ekbuf[(base + r) * HH + h] = __builtin_exp2f(C * sk);
  eqbuf[(base + r) * HH + h] = __builtin_exp2f(C * sq);
}

// ---------------- Stage 2: adj -> adjT (bf16) -------------------------------
__global__ __launch_bounds__(256) void transpose_kernel(const float* __restrict__ adj,
                                                        unsigned short* __restrict__ adjT) {
  __shared__ float t[64][65];
  int b = blockIdx.z;
  int c0 = blockIdx.x * 64, r0 = blockIdx.y * 64;
  const float* ab = adj + (size_t)b * GN * GN;
  unsigned short* ob = adjT + (size_t)b * GN * GN;
  int tid = threadIdx.x;
#pragma unroll
  for (int k = 0; k < 4; ++k) {
    int v = tid + k * 256;
    int row = v >> 4, seg = v & 15;
    v4f f = *(const v4f*)(ab + (size_t)(r0 + row) * GN + c0 + seg * 4);
    t[row][seg * 4 + 0] = f[0];
    t[row][seg * 4 + 1] = f[1];
    t[row][seg * 4 + 2] = f[2];
    t[row][seg * 4 + 3] = f[3];
  }
  __syncthreads();
  int c = tid >> 2;            // output row = original column
  int rs = (tid & 3) * 16;     // 16 output cols = original rows
  v4u p0, p1;
#pragma unroll
  for (int j = 0; j < 4; ++j) {
    p0[j] = pack2(t[rs + 2 * j][c], t[rs + 2 * j + 1][c]);
    p1[j] = pack2(t[rs + 8 + 2 * j][c], t[rs + 9 + 2 * j][c]);
  }
  unsigned short* dst = ob + (size_t)(c0 + c) * GN + r0 + rs;
  *(v4u*)dst = p0;
  *(v4u*)(dst + 8) = p1;
}

// ---------------- Stage 3: e-scores via exp-product, stored transposed ------
// Et[b][m][n] = asum - sum_h (2*a[h]) / (eq[b,m,h]*ek[b,n,h] + 1)
__global__ __launch_bounds__(256) void escore_kernel(const float* __restrict__ ek,
                                                     const float* __restrict__ eq,
                                                     const float* __restrict__ avec,
                                                     unsigned short* __restrict__ Et) {
  __shared__ float kl[64][36], ql[64][36];
  int b = blockIdx.z;
  int n0 = blockIdx.x * 64, m0 = blockIdx.y * 64;
  const float* kb = ek + ((size_t)b * GN + n0) * HH;
  const float* qb = eq + ((size_t)b * GN + m0) * HH;
  int tid = threadIdx.x;
#pragma unroll
  for (int k = 0; k < 2; ++k) {
    int v = tid + k * 256;
    int row = v >> 3, seg = v & 7;
    *(v4f*)&kl[row][seg * 4] = *(const v4f*)(kb + row * HH + seg * 4);
    *(v4f*)&ql[row][seg * 4] = *(const v4f*)(qb + row * HH + seg * 4);
  }
  // wave-uniform: a2[h] = 2*a[h] (SGPR-resident), asum = sum a[h]
  float a2[HH];
  float asum = 0.f;
#pragma unroll
  for (int h = 0; h < HH; ++h) {
    float av = avec[h];
    a2[h] = 2.0f * av;
    asum += av;
  }
  __syncthreads();
  int m = tid >> 2, ng = tid & 3;
  v4f qv[8];
#pragma unroll
  for (int h4 = 0; h4 < 8; ++h4) qv[h4] = *(const v4f*)&ql[m][h4 * 4];
  unsigned short* dst = Et + ((size_t)b * GN + m0 + m) * GN + n0;
#pragma unroll 4
  for (int jj = 0; jj < 16; ++jj) {
    int n = jj * 4 + ng;  // stride-4 interleave: conflict-free kl reads
    float acc = 0.f;
#pragma unroll
    for (int h4 = 0; h4 < 8; ++h4) {
      v4f kv = *(const v4f*)&kl[n][h4 * 4];
      v4f f = kv * qv[h4] + 1.0f;  // v_pk_fma-able
#pragma unroll
      for (int e = 0; e < 4; ++e) {
        float r = __builtin_amdgcn_rcpf(f[e]);
        acc += a2[h4 * 4 + e] * r;
      }
    }
    dst[n] = (unsigned short)f2bf(asum - acc);
  }
}

// ---------------- Stage 4/5: batched GEMM, C = A * Bt^T ---------------------
// A row-major [512][512] (f32 or bf16), Bt row-major [col][k] bf16.
// 128x128 tile, BK=32, 4 waves, 4x4 fragments of mfma_f32_16x16x32_bf16.
template <bool AFLOAT, bool OUTF32>
__global__ __launch_bounds__(256) void gemm_bt(const void* __restrict__ Av,
                                               const unsigned short* __restrict__ Bt,
                                               void* __restrict__ Cv) {
  __shared__ unsigned short At[128 * 40];  // +8 pad: row stride 80B -> 2-way conflicts only
  __shared__ unsigned short Bs[128 * 40];
  int b = blockIdx.z;
  int row0 = blockIdx.y * 128, col0 = blockIdx.x * 128;
  int tid = threadIdx.x;
  int lane = tid & 63, wave = tid >> 6;
  int wr = wave >> 1, wc = wave & 1;
  int srow = tid >> 1, shalf = tid & 1;

  v4f acc[4][4];
#pragma unroll
  for (int i = 0; i < 4; ++i)
#pragma unroll
    for (int j = 0; j < 4; ++j) acc[i][j] = (v4f){0.f, 0.f, 0.f, 0.f};

  const float* Af = (const float*)Av + (size_t)b * GN * GN + (size_t)(row0 + srow) * GN;
  const unsigned short* Ah =
      (const unsigned short*)Av + (size_t)b * GN * GN + (size_t)(row0 + srow) * GN;
  const unsigned short* Bp = Bt + (size_t)b * GN * GN + (size_t)(col0 + srow) * GN;

  for (int kt = 0; kt < GN / 32; ++kt) {
    int kb = kt * 32 + shalf * 16;
    v4u a0, a1;
    if constexpr (AFLOAT) {
      v4f f0 = *(const v4f*)(Af + kb);
      v4f f1 = *(const v4f*)(Af + kb + 4);
      v4f f2 = *(const v4f*)(Af + kb + 8);
      v4f f3 = *(const v4f*)(Af + kb + 12);
      a0[0] = pack2(f0[0], f0[1]); a0[1] = pack2(f0[2], f0[3]);
      a0[2] = pack2(f1[0], f1[1]); a0[3] = pack2(f1[2], f1[3]);
      a1[0] = pack2(f2[0], f2[1]); a1[1] = pack2(f2[2], f2[3]);
      a1[2] = pack2(f3[0], f3[1]); a1[3] = pack2(f3[2], f3[3]);
    } else {
      a0 = *(const v4u*)(Ah + kb);
      a1 = *(const v4u*)(Ah + kb + 8);
    }
    v4u bb0 = *(const v4u*)(Bp + kb);
    v4u bb1 = *(const v4u*)(Bp + kb + 8);
    __syncthreads();  // previous iteration's MFMA reads done
    {
      v4u* ad = (v4u*)&At[srow * 40 + shalf * 16];
      ad[0] = a0; ad[1] = a1;
      v4u* bd = (v4u*)&Bs[srow * 40 + shalf * 16];
      bd[0] = bb0; bd[1] = bb1;
    }
    __syncthreads();
    int ko = (lane >> 4) * 8;
    int lr = lane & 15;
    v8bf af[4], bf[4];
#pragma unroll
    for (int i = 0; i < 4; ++i)
      af[i] = *(const v8bf*)&At[(wr * 64 + i * 16 + lr) * 40 + ko];
#pragma unroll
    for (int j = 0; j < 4; ++j)
      bf[j] = *(const v8bf*)&Bs[(wc * 64 + j * 16 + lr) * 40 + ko];
#pragma unroll
    for (int i = 0; i < 4; ++i)
#pragma unroll
      for (int j = 0; j < 4; ++j)
        acc[i][j] = __builtin_amdgcn_mfma_f32_16x16x32_bf16(af[i], bf[j], acc[i][j], 0, 0, 0);
  }

  int lc = lane & 15;
  int lrow4 = (lane >> 4) * 4;
#pragma unroll
  for (int i = 0; i < 4; ++i) {
#pragma unroll
    for (int j = 0; j < 4; ++j) {
      int gr = row0 + wr * 64 + i * 16 + lrow4;
      int gc = col0 + wc * 64 + j * 16 + lc;
#pragma unroll
      for (int e = 0; e < 4; ++e) {
        float v = acc[i][j][e];
        if constexpr (OUTF32)
          ((float*)Cv)[(size_t)b * GN * GN + (size_t)(gr + e) * GN + gc] = v;
        else
          ((unsigned short*)Cv)[(size_t)b * GN * GN + (size_t)(gr + e) * GN + gc] =
              (unsigned short)f2bf(v);
      }
    }
  }
}

// ---------------- launch ----------------------------------------------------
extern "C" void kernel_launch(void* const* d_in, const int* in_sizes, int n_in,
                              void* d_out, int out_size, void* d_ws, size_t ws_size,
                              hipStream_t stream) {
  const float* receiver  = (const float*)d_in[0];
  const float* attendant = (const float*)d_in[1];
  const float* adj       = (const float*)d_in[2];
  const float* wq        = (const float*)d_in[3];
  const float* wk        = (const float*)d_in[4];
  const float* bias      = (const float*)d_in[5];
  const float* avec      = (const float*)d_in[6];
  float* out = (float*)d_out;

  char* ws = (char*)d_ws;
  float* ekbuf          = (float*)(ws);                          // 2 MiB
  float* eqbuf          = (float*)(ws + (2u << 20));             // 2 MiB
  unsigned short* Et    = (unsigned short*)(ws + (4u << 20));    // 16 MiB
  unsigned short* adjT  = (unsigned short*)(ws + (20u << 20));   // 16 MiB
  unsigned short* Tbuf  = (unsigned short*)(ws + (36u << 20));   // 16 MiB

  kq_kernel<<<dim3(2048), dim3(256), 0, stream>>>(receiver, attendant, wq, wk, bias,
                                                  ekbuf, eqbuf);
  transpose_kernel<<<dim3(8, 8, 32), dim3(256), 0, stream>>>(adj, adjT);
  escore_kernel<<<dim3(8, 8, 32), dim3(256), 0, stream>>>(ekbuf, eqbuf, avec, Et);
  // T = adj (f32) @ Et^T  -> bf16
  gemm_bt<true, false><<<dim3(4, 4, 32), dim3(256), 0, stream>>>(adj, Et, Tbuf);
  // out = T (bf16) @ adjT^T -> f32
  gemm_bt<false, true><<<dim3(4, 4, 32), dim3(256), 0, stream>>>(Tbuf, adjT, out);
}

// Round 3
// 96.878 us; speedup vs baseline: 1.4961x; 1.1274x over previous
//
#include <hip/hip_runtime.h>

#define GN 512
#define HH 32
#define DD 64

typedef float v4f __attribute__((ext_vector_type(4)));
typedef unsigned int v4u __attribute__((ext_vector_type(4)));
typedef unsigned int u32;
typedef __bf16 v8bf __attribute__((ext_vector_type(8)));

__device__ __forceinline__ u32 f2bf(float f) {
  u32 u = __builtin_bit_cast(u32, f);
  return (u + 0x7fffu + ((u >> 16) & 1u)) >> 16;
}
__device__ __forceinline__ u32 pack2(float a, float b) {
  return f2bf(a) | (f2bf(b) << 16);
}

#define GLOAD16(g, l)                                                              \
  __builtin_amdgcn_global_load_lds((const __attribute__((address_space(1))) u32*)(g), \
                                   (__attribute__((address_space(3))) u32*)(l), 16, 0, 0)

// ---------------- Stage 1: projections -> exp space -------------------------
// ek[b,n,h] = exp(2*(receiver@w_k + bias))   eq[b,n,h] = exp(2*(attendant@w_q))
__global__ __launch_bounds__(256) void kq_kernel(const float* __restrict__ rec,
                                                 const float* __restrict__ att,
                                                 const float* __restrict__ wq,
                                                 const float* __restrict__ wk,
                                                 const float* __restrict__ bias,
                                                 float* __restrict__ ekbuf,
                                                 float* __restrict__ eqbuf) {
  __shared__ float rr[512], ra[512];
  int tid = threadIdx.x;
  size_t base = (size_t)blockIdx.x * 8;
  const float* gr = rec + base * DD;
  const float* ga = att + base * DD;
  rr[tid] = gr[tid]; rr[tid + 256] = gr[tid + 256];
  ra[tid] = ga[tid]; ra[tid + 256] = ga[tid + 256];
  __syncthreads();
  int r = tid >> 5, h = tid & 31;
  float sk = bias[h], sq = 0.f;
  const float* rrow = &rr[r * DD];
  const float* arow = &ra[r * DD];
#pragma unroll 8
  for (int d = 0; d < DD; ++d) {
    sk += rrow[d] * wk[d * HH + h];
    sq += arow[d] * wq[d * HH + h];
  }
  const float C = 2.8853900817779268f;  // 2*log2(e)
  ekbuf[(base + r) * HH + h] = __builtin_exp2f(C * sk);
  eqbuf[(base + r) * HH + h] = __builtin_exp2f(C * sq);
}

// ---------------- Stage 2: adj -> adjT (bf16) + adjBF (bf16 row-major) ------
__global__ __launch_bounds__(256) void transpose_kernel(const float* __restrict__ adj,
                                                        unsigned short* __restrict__ adjT,
                                                        unsigned short* __restrict__ adjBF) {
  __shared__ float t[64][65];
  int b = blockIdx.z;
  int c0 = blockIdx.x * 64, r0 = blockIdx.y * 64;
  const float* ab = adj + (size_t)b * GN * GN;
  unsigned short* ob = adjT + (size_t)b * GN * GN;
  unsigned short* of = adjBF + (size_t)b * GN * GN;
  int tid = threadIdx.x;
#pragma unroll
  for (int k = 0; k < 4; ++k) {
    int v = tid + k * 256;
    int row = v >> 4, seg = v & 15;
    v4f f = *(const v4f*)(ab + (size_t)(r0 + row) * GN + c0 + seg * 4);
    t[row][seg * 4 + 0] = f[0];
    t[row][seg * 4 + 1] = f[1];
    t[row][seg * 4 + 2] = f[2];
    t[row][seg * 4 + 3] = f[3];
    // row-major bf16 copy, straight from registers
    u32 p[2] = {pack2(f[0], f[1]), pack2(f[2], f[3])};
    *(u32*)(of + (size_t)(r0 + row) * GN + c0 + seg * 4) = p[0];
    *(u32*)(of + (size_t)(r0 + row) * GN + c0 + seg * 4 + 2) = p[1];
  }
  __syncthreads();
  int c = tid >> 2;
  int rs = (tid & 3) * 16;
  v4u p0, p1;
#pragma unroll
  for (int j = 0; j < 4; ++j) {
    p0[j] = pack2(t[rs + 2 * j][c], t[rs + 2 * j + 1][c]);
    p1[j] = pack2(t[rs + 8 + 2 * j][c], t[rs + 9 + 2 * j][c]);
  }
  unsigned short* dst = ob + (size_t)(c0 + c) * GN + r0 + rs;
  *(v4u*)dst = p0;
  *(v4u*)(dst + 8) = p1;
}

// ---------------- Stage 3: e-scores via exp-product, stored transposed ------
// Et[b][m][n] = asum - sum_h (2*a[h]) / (eq[b,m,h]*ek[b,n,h] + 1)
__global__ __launch_bounds__(256) void escore_kernel(const float* __restrict__ ek,
                                                     const float* __restrict__ eq,
                                                     const float* __restrict__ avec,
                                                     unsigned short* __restrict__ Et) {
  __shared__ float kl[64][36], ql[64][36];
  int b = blockIdx.z;
  int n0 = blockIdx.x * 64, m0 = blockIdx.y * 64;
  const float* kb = ek + ((size_t)b * GN + n0) * HH;
  const float* qb = eq + ((size_t)b * GN + m0) * HH;
  int tid = threadIdx.x;
#pragma unroll
  for (int k = 0; k < 2; ++k) {
    int v = tid + k * 256;
    int row = v >> 3, seg = v & 7;
    *(v4f*)&kl[row][seg * 4] = *(const v4f*)(kb + row * HH + seg * 4);
    *(v4f*)&ql[row][seg * 4] = *(const v4f*)(qb + row * HH + seg * 4);
  }
  // wave-uniform constants
  v4f a2v[8];
  float asum = 0.f;
#pragma unroll
  for (int h4 = 0; h4 < 8; ++h4) {
    v4f av = *(const v4f*)(avec + h4 * 4);
    a2v[h4] = av * 2.0f;
    asum += av[0] + av[1] + av[2] + av[3];
  }
  __syncthreads();
  int m = tid >> 2, ng = tid & 3;
  v4f qv[8];
#pragma unroll
  for (int h4 = 0; h4 < 8; ++h4) qv[h4] = *(const v4f*)&ql[m][h4 * 4];
  u32* dstw = (u32*)(Et + ((size_t)b * GN + m0 + m) * GN + n0);
#pragma unroll 2
  for (int nn = 0; nn < 8; ++nn) {
    int n = ng * 2 + nn * 8;  // pair (n, n+1); 4 ng-groups hit 4 distinct banks
    v4f acc0 = (v4f){0.f, 0.f, 0.f, 0.f};
    v4f acc1 = (v4f){0.f, 0.f, 0.f, 0.f};
#pragma unroll
    for (int h4 = 0; h4 < 8; ++h4) {
      v4f kv0 = *(const v4f*)&kl[n][h4 * 4];
      v4f kv1 = *(const v4f*)&kl[n + 1][h4 * 4];
      v4f f0 = kv0 * qv[h4] + 1.0f;
      v4f f1 = kv1 * qv[h4] + 1.0f;
      v4f r0, r1;
#pragma unroll
      for (int e = 0; e < 4; ++e) {
        r0[e] = __builtin_amdgcn_rcpf(f0[e]);
        r1[e] = __builtin_amdgcn_rcpf(f1[e]);
      }
      acc0 += a2v[h4] * r0;
      acc1 += a2v[h4] * r1;
    }
    float s0 = asum - (acc0[0] + acc0[1] + acc0[2] + acc0[3]);
    float s1 = asum - (acc1[0] + acc1[1] + acc1[2] + acc1[3]);
    __bf16 b0 = (__bf16)s0, b1 = (__bf16)s1;
    u32 w = (u32)__builtin_bit_cast(unsigned short, b0) |
            ((u32)__builtin_bit_cast(unsigned short, b1) << 16);
    dstw[n >> 1] = w;
  }
}

// ---------------- Stage 4/5: batched bf16 GEMM, C = A * Bt^T ----------------
// A, Bt row-major bf16 [512][512]. 128x128 tile, BK=64, global_load_lds
// staging with source-side XOR swizzle (slot ^= row&7 on 16B slots).
#define SWZ(r, s) ((s) ^ ((r) & 7))

template <bool OUTF32>
__global__ __launch_bounds__(256) void gemm_bt(const unsigned short* __restrict__ A,
                                               const unsigned short* __restrict__ Bt,
                                               void* __restrict__ Cv) {
  __shared__ unsigned short At[128 * 64];  // 16 KiB, linear (gload_lds dest)
  __shared__ unsigned short Bs[128 * 64];
  int b = blockIdx.z;
  int row0 = blockIdx.y * 128, col0 = blockIdx.x * 128;
  int tid = threadIdx.x, lane = tid & 63, wave = tid >> 6;
  int wr = wave >> 1, wc = wave & 1;
  const unsigned short* Ab = A + (size_t)b * GN * GN;
  const unsigned short* Bb = Bt + (size_t)b * GN * GN;

  v4f acc[4][4];
#pragma unroll
  for (int i = 0; i < 4; ++i)
#pragma unroll
    for (int j = 0; j < 4; ++j) acc[i][j] = (v4f){0.f, 0.f, 0.f, 0.f};

  // staging chunk geometry: 1024 16B-chunks per tile; chunk c -> row=c>>3, slot=c&7
  for (int kt = 0; kt < GN / 64; ++kt) {
    __syncthreads();  // previous iteration's LDS reads drained
#pragma unroll
    for (int i = 0; i < 4; ++i) {
      int c = i * 256 + tid;
      int r = c >> 3, s = c & 7;
      const unsigned short* ga = Ab + (size_t)(row0 + r) * GN + kt * 64 + SWZ(r, s) * 8;
      const unsigned short* gb = Bb + (size_t)(col0 + r) * GN + kt * 64 + SWZ(r, s) * 8;
      char* la = (char*)At + (i * 256 + wave * 64) * 16;
      char* lb = (char*)Bs + (i * 256 + wave * 64) * 16;
      GLOAD16(ga, la);
      GLOAD16(gb, lb);
    }
    asm volatile("s_waitcnt vmcnt(0)" ::: "memory");
    __syncthreads();
    int lr = lane & 15, s16 = lane >> 4;
#pragma unroll
    for (int h = 0; h < 2; ++h) {  // k-halves of BK=64
      int sl = h * 4 + s16;
      v8bf af[4], bfv[4];
#pragma unroll
      for (int i = 0; i < 4; ++i) {
        int r = wr * 64 + i * 16 + lr;
        af[i] = *(const v8bf*)&At[r * 64 + SWZ(r, sl) * 8];
      }
#pragma unroll
      for (int j = 0; j < 4; ++j) {
        int r = wc * 64 + j * 16 + lr;
        bfv[j] = *(const v8bf*)&Bs[r * 64 + SWZ(r, sl) * 8];
      }
#pragma unroll
      for (int i = 0; i < 4; ++i)
#pragma unroll
        for (int j = 0; j < 4; ++j)
          acc[i][j] = __builtin_amdgcn_mfma_f32_16x16x32_bf16(af[i], bfv[j], acc[i][j], 0, 0, 0);
    }
  }

  int lc = lane & 15;
  int lrow4 = (lane >> 4) * 4;
#pragma unroll
  for (int i = 0; i < 4; ++i) {
#pragma unroll
    for (int j = 0; j < 4; ++j) {
      int gr = row0 + wr * 64 + i * 16 + lrow4;
      int gc = col0 + wc * 64 + j * 16 + lc;
#pragma unroll
      for (int e = 0; e < 4; ++e) {
        float v = acc[i][j][e];
        if constexpr (OUTF32)
          ((float*)Cv)[(size_t)b * GN * GN + (size_t)(gr + e) * GN + gc] = v;
        else
          ((unsigned short*)Cv)[(size_t)b * GN * GN + (size_t)(gr + e) * GN + gc] =
              (unsigned short)f2bf(v);
      }
    }
  }
}

// ---------------- launch ----------------------------------------------------
extern "C" void kernel_launch(void* const* d_in, const int* in_sizes, int n_in,
                              void* d_out, int out_size, void* d_ws, size_t ws_size,
                              hipStream_t stream) {
  const float* receiver  = (const float*)d_in[0];
  const float* attendant = (const float*)d_in[1];
  const float* adj       = (const float*)d_in[2];
  const float* wq        = (const float*)d_in[3];
  const float* wk        = (const float*)d_in[4];
  const float* bias      = (const float*)d_in[5];
  const float* avec      = (const float*)d_in[6];
  float* out = (float*)d_out;

  char* ws = (char*)d_ws;
  float* ekbuf          = (float*)(ws);                          // 2 MiB
  float* eqbuf          = (float*)(ws + (2u << 20));             // 2 MiB
  unsigned short* Et    = (unsigned short*)(ws + (4u << 20));    // 16 MiB
  unsigned short* adjT  = (unsigned short*)(ws + (20u << 20));   // 16 MiB
  unsigned short* adjBF = (unsigned short*)(ws + (36u << 20));   // 16 MiB
  unsigned short* Tbuf  = (unsigned short*)(ws + (52u << 20));   // 16 MiB

  kq_kernel<<<dim3(2048), dim3(256), 0, stream>>>(receiver, attendant, wq, wk, bias,
                                                  ekbuf, eqbuf);
  transpose_kernel<<<dim3(8, 8, 32), dim3(256), 0, stream>>>(adj, adjT, adjBF);
  escore_kernel<<<dim3(8, 8, 32), dim3(256), 0, stream>>>(ekbuf, eqbuf, avec, Et);
  // T = adjBF @ Et^T  -> bf16
  gemm_bt<false><<<dim3(4, 4, 32), dim3(256), 0, stream>>>(adjBF, Et, Tbuf);
  // out = Tbuf @ adjT^T -> f32
  gemm_bt<true><<<dim3(4, 4, 32), dim3(256), 0, stream>>>(Tbuf, adjT, out);
}

// Round 4
// 96.650 us; speedup vs baseline: 1.4997x; 1.0024x over previous
//
#include <hip/hip_runtime.h>

#define GN 512
#define HH 32
#define DD 64

typedef float v4f __attribute__((ext_vector_type(4)));
typedef unsigned int v4u __attribute__((ext_vector_type(4)));
typedef unsigned int u32;
typedef __bf16 v8bf __attribute__((ext_vector_type(8)));

__device__ __forceinline__ u32 f2bf(float f) {
  u32 u = __builtin_bit_cast(u32, f);
  return (u + 0x7fffu + ((u >> 16) & 1u)) >> 16;
}
__device__ __forceinline__ u32 pack2(float a, float b) {
  return f2bf(a) | (f2bf(b) << 16);
}

#define GLOAD16(g, l)                                                              \
  __builtin_amdgcn_global_load_lds((const __attribute__((address_space(1))) u32*)(g), \
                                   (__attribute__((address_space(3))) u32*)(l), 16, 0, 0)
#define VMCNT0 asm volatile("s_waitcnt vmcnt(0)" ::: "memory")

// ---------------- Stage 1: projections -> exp space -------------------------
__global__ __launch_bounds__(256) void kq_kernel(const float* __restrict__ rec,
                                                 const float* __restrict__ att,
                                                 const float* __restrict__ wq,
                                                 const float* __restrict__ wk,
                                                 const float* __restrict__ bias,
                                                 float* __restrict__ ekbuf,
                                                 float* __restrict__ eqbuf) {
  __shared__ float rr[512], ra[512];
  int tid = threadIdx.x;
  size_t base = (size_t)blockIdx.x * 8;
  const float* gr = rec + base * DD;
  const float* ga = att + base * DD;
  rr[tid] = gr[tid]; rr[tid + 256] = gr[tid + 256];
  ra[tid] = ga[tid]; ra[tid + 256] = ga[tid + 256];
  __syncthreads();
  int r = tid >> 5, h = tid & 31;
  float sk = bias[h], sq = 0.f;
  const float* rrow = &rr[r * DD];
  const float* arow = &ra[r * DD];
#pragma unroll 8
  for (int d = 0; d < DD; ++d) {
    sk += rrow[d] * wk[d * HH + h];
    sq += arow[d] * wq[d * HH + h];
  }
  const float C = 2.8853900817779268f;  // 2*log2(e)
  ekbuf[(base + r) * HH + h] = __builtin_exp2f(C * sk);
  eqbuf[(base + r) * HH + h] = __builtin_exp2f(C * sq);
}

// ---------------- Stage 2: adj -> adjT (bf16) + adjBF (bf16 row-major) ------
__global__ __launch_bounds__(256) void transpose_kernel(const float* __restrict__ adj,
                                                        unsigned short* __restrict__ adjT,
                                                        unsigned short* __restrict__ adjBF) {
  __shared__ float t[64][65];
  int b = blockIdx.z;
  int c0 = blockIdx.x * 64, r0 = blockIdx.y * 64;
  const float* ab = adj + (size_t)b * GN * GN;
  unsigned short* ob = adjT + (size_t)b * GN * GN;
  unsigned short* of = adjBF + (size_t)b * GN * GN;
  int tid = threadIdx.x;
#pragma unroll
  for (int k = 0; k < 4; ++k) {
    int v = tid + k * 256;
    int row = v >> 4, seg = v & 15;
    v4f f = *(const v4f*)(ab + (size_t)(r0 + row) * GN + c0 + seg * 4);
    t[row][seg * 4 + 0] = f[0];
    t[row][seg * 4 + 1] = f[1];
    t[row][seg * 4 + 2] = f[2];
    t[row][seg * 4 + 3] = f[3];
    typedef u32 v2u __attribute__((ext_vector_type(2)));
    v2u p = {pack2(f[0], f[1]), pack2(f[2], f[3])};
    *(v2u*)(of + (size_t)(r0 + row) * GN + c0 + seg * 4) = p;
  }
  __syncthreads();
  int c = tid >> 2;
  int rs = (tid & 3) * 16;
  v4u p0, p1;
#pragma unroll
  for (int j = 0; j < 4; ++j) {
    p0[j] = pack2(t[rs + 2 * j][c], t[rs + 2 * j + 1][c]);
    p1[j] = pack2(t[rs + 8 + 2 * j][c], t[rs + 9 + 2 * j][c]);
  }
  unsigned short* dst = ob + (size_t)(c0 + c) * GN + r0 + rs;
  *(v4u*)dst = p0;
  *(v4u*)(dst + 8) = p1;
}

// ---------------- Stage 3: e-scores via exp-product, stored transposed ------
__global__ __launch_bounds__(256) void escore_kernel(const float* __restrict__ ek,
                                                     const float* __restrict__ eq,
                                                     const float* __restrict__ avec,
                                                     unsigned short* __restrict__ Et) {
  __shared__ float kl[64][36], ql[64][36];
  int b = blockIdx.z;
  int n0 = blockIdx.x * 64, m0 = blockIdx.y * 64;
  const float* kb = ek + ((size_t)b * GN + n0) * HH;
  const float* qb = eq + ((size_t)b * GN + m0) * HH;
  int tid = threadIdx.x;
#pragma unroll
  for (int k = 0; k < 2; ++k) {
    int v = tid + k * 256;
    int row = v >> 3, seg = v & 7;
    *(v4f*)&kl[row][seg * 4] = *(const v4f*)(kb + row * HH + seg * 4);
    *(v4f*)&ql[row][seg * 4] = *(const v4f*)(qb + row * HH + seg * 4);
  }
  v4f a2v[8];
  float asum = 0.f;
#pragma unroll
  for (int h4 = 0; h4 < 8; ++h4) {
    v4f av = *(const v4f*)(avec + h4 * 4);
    a2v[h4] = av * 2.0f;
    asum += av[0] + av[1] + av[2] + av[3];
  }
  __syncthreads();
  int m = tid >> 2, ng = tid & 3;
  v4f qv[8];
#pragma unroll
  for (int h4 = 0; h4 < 8; ++h4) qv[h4] = *(const v4f*)&ql[m][h4 * 4];
  u32* dstw = (u32*)(Et + ((size_t)b * GN + m0 + m) * GN + n0);
#pragma unroll 2
  for (int nn = 0; nn < 8; ++nn) {
    int n = ng * 2 + nn * 8;
    v4f acc0 = (v4f){0.f, 0.f, 0.f, 0.f};
    v4f acc1 = (v4f){0.f, 0.f, 0.f, 0.f};
#pragma unroll
    for (int h4 = 0; h4 < 8; ++h4) {
      v4f kv0 = *(const v4f*)&kl[n][h4 * 4];
      v4f kv1 = *(const v4f*)&kl[n + 1][h4 * 4];
      v4f f0 = kv0 * qv[h4] + 1.0f;
      v4f f1 = kv1 * qv[h4] + 1.0f;
      v4f r0, r1;
#pragma unroll
      for (int e = 0; e < 4; ++e) {
        r0[e] = __builtin_amdgcn_rcpf(f0[e]);
        r1[e] = __builtin_amdgcn_rcpf(f1[e]);
      }
      acc0 += a2v[h4] * r0;
      acc1 += a2v[h4] * r1;
    }
    float s0 = asum - (acc0[0] + acc0[1] + acc0[2] + acc0[3]);
    float s1 = asum - (acc1[0] + acc1[1] + acc1[2] + acc1[3]);
    __bf16 b0 = (__bf16)s0, b1 = (__bf16)s1;
    u32 w = (u32)__builtin_bit_cast(unsigned short, b0) |
            ((u32)__builtin_bit_cast(unsigned short, b1) << 16);
    dstw[n >> 1] = w;
  }
}

// ---------------- Stage 4/5: batched bf16 GEMM, 2-phase pipelined -----------
// A, Bt row-major bf16 [512][512]. 128x128 tile, BK=64, double-buffered LDS,
// global_load_lds with source-side XOR swizzle, raw s_barrier (1/K-step).
#define SWZ(r, s) ((s) ^ ((r) & 7))

template <bool OUTF32>
__global__ __launch_bounds__(256) void gemm_bt(const unsigned short* __restrict__ A,
                                               const unsigned short* __restrict__ Bt,
                                               void* __restrict__ Cv) {
  __shared__ unsigned short At[2][128 * 64];  // 2 x 16 KiB
  __shared__ unsigned short Bs[2][128 * 64];
  int b = blockIdx.z;
  int row0 = blockIdx.y * 128, col0 = blockIdx.x * 128;
  int tid = threadIdx.x, lane = tid & 63, wave = tid >> 6;
  int wr = wave >> 1, wc = wave & 1;
  const unsigned short* Ab = A + (size_t)b * GN * GN;
  const unsigned short* Bb = Bt + (size_t)b * GN * GN;

  v4f acc[4][4];
#pragma unroll
  for (int i = 0; i < 4; ++i)
#pragma unroll
    for (int j = 0; j < 4; ++j) acc[i][j] = (v4f){0.f, 0.f, 0.f, 0.f};

  // per-thread staging: 4 A-chunks + 4 B-chunks of 16B per K-tile
  int cc_r[4], cc_s[4];
#pragma unroll
  for (int i = 0; i < 4; ++i) {
    int c = i * 256 + tid;
    cc_r[i] = c >> 3;
    cc_s[i] = SWZ(c >> 3, c & 7);
  }

#define STAGE(buf, kt)                                                                   \
  {                                                                                      \
    _Pragma("unroll") for (int i = 0; i < 4; ++i) {                                      \
      const unsigned short* ga = Ab + (size_t)(row0 + cc_r[i]) * GN + (kt)*64 + cc_s[i] * 8; \
      const unsigned short* gb = Bb + (size_t)(col0 + cc_r[i]) * GN + (kt)*64 + cc_s[i] * 8; \
      GLOAD16(ga, (char*)&At[buf][0] + (i * 256 + wave * 64) * 16);                      \
      GLOAD16(gb, (char*)&Bs[buf][0] + (i * 256 + wave * 64) * 16);                      \
    }                                                                                    \
  }

#define COMPUTE(buf)                                                                     \
  {                                                                                      \
    int lr = lane & 15, s16 = lane >> 4;                                                 \
    _Pragma("unroll") for (int h = 0; h < 2; ++h) {                                      \
      int sl = h * 4 + s16;                                                              \
      v8bf af[4], bfv[4];                                                                \
      _Pragma("unroll") for (int i = 0; i < 4; ++i) {                                    \
        int r = wr * 64 + i * 16 + lr;                                                   \
        af[i] = *(const v8bf*)&At[buf][r * 64 + SWZ(r, sl) * 8];                         \
      }                                                                                  \
      _Pragma("unroll") for (int j = 0; j < 4; ++j) {                                    \
        int r = wc * 64 + j * 16 + lr;                                                   \
        bfv[j] = *(const v8bf*)&Bs[buf][r * 64 + SWZ(r, sl) * 8];                        \
      }                                                                                  \
      _Pragma("unroll") for (int i = 0; i < 4; ++i)                                      \
          _Pragma("unroll") for (int j = 0; j < 4; ++j) acc[i][j] =                      \
          __builtin_amdgcn_mfma_f32_16x16x32_bf16(af[i], bfv[j], acc[i][j], 0, 0, 0);    \
    }                                                                                    \
  }

  STAGE(0, 0);
  VMCNT0;
  __builtin_amdgcn_s_barrier();
#pragma unroll
  for (int kt = 0; kt < 7; ++kt) {
    int cur = kt & 1;
    STAGE(cur ^ 1, kt + 1);   // prefetch next tile (in flight during compute)
    COMPUTE(cur);
    VMCNT0;                   // prefetch landed
    __builtin_amdgcn_s_barrier();
  }
  COMPUTE(1);

  int lc = lane & 15;
  int lrow4 = (lane >> 4) * 4;
#pragma unroll
  for (int i = 0; i < 4; ++i) {
#pragma unroll
    for (int j = 0; j < 4; ++j) {
      int gr = row0 + wr * 64 + i * 16 + lrow4;
      int gc = col0 + wc * 64 + j * 16 + lc;
#pragma unroll
      for (int e = 0; e < 4; ++e) {
        float v = acc[i][j][e];
        if constexpr (OUTF32)
          ((float*)Cv)[(size_t)b * GN * GN + (size_t)(gr + e) * GN + gc] = v;
        else
          ((unsigned short*)Cv)[(size_t)b * GN * GN + (size_t)(gr + e) * GN + gc] =
              (unsigned short)f2bf(v);
      }
    }
  }
#undef STAGE
#undef COMPUTE
}

// ---------------- launch ----------------------------------------------------
extern "C" void kernel_launch(void* const* d_in, const int* in_sizes, int n_in,
                              void* d_out, int out_size, void* d_ws, size_t ws_size,
                              hipStream_t stream) {
  const float* receiver  = (const float*)d_in[0];
  const float* attendant = (const float*)d_in[1];
  const float* adj       = (const float*)d_in[2];
  const float* wq        = (const float*)d_in[3];
  const float* wk        = (const float*)d_in[4];
  const float* bias      = (const float*)d_in[5];
  const float* avec      = (const float*)d_in[6];
  float* out = (float*)d_out;

  char* ws = (char*)d_ws;
  float* ekbuf          = (float*)(ws);                          // 2 MiB
  float* eqbuf          = (float*)(ws + (2u << 20));             // 2 MiB
  unsigned short* Et    = (unsigned short*)(ws + (4u << 20));    // 16 MiB
  unsigned short* adjT  = (unsigned short*)(ws + (20u << 20));   // 16 MiB
  unsigned short* adjBF = (unsigned short*)(ws + (36u << 20));   // 16 MiB
  unsigned short* Tbuf  = (unsigned short*)(ws + (52u << 20));   // 16 MiB

  kq_kernel<<<dim3(2048), dim3(256), 0, stream>>>(receiver, attendant, wq, wk, bias,
                                                  ekbuf, eqbuf);
  transpose_kernel<<<dim3(8, 8, 32), dim3(256), 0, stream>>>(adj, adjT, adjBF);
  escore_kernel<<<dim3(8, 8, 32), dim3(256), 0, stream>>>(ekbuf, eqbuf, avec, Et);
  // T = adjBF @ Et^T  -> bf16
  gemm_bt<false><<<dim3(4, 4, 32), dim3(256), 0, stream>>>(adjBF, Et, Tbuf);
  // out = Tbuf @ adjT^T -> f32
  gemm_bt<true><<<dim3(4, 4, 32), dim3(256), 0, stream>>>(Tbuf, adjT, out);
}

// Round 5
// 90.346 us; speedup vs baseline: 1.6043x; 1.0698x over previous
//
#include <hip/hip_runtime.h>

#define GN 512
#define HH 32
#define DD 64

typedef float v4f __attribute__((ext_vector_type(4)));
typedef unsigned int v4u __attribute__((ext_vector_type(4)));
typedef u_int32_t u32;
typedef u32 v2u __attribute__((ext_vector_type(2)));
typedef __bf16 v8bf __attribute__((ext_vector_type(8)));

__device__ __forceinline__ u32 f2bf(float f) {
  u32 u = __builtin_bit_cast(u32, f);
  return (u + 0x7fffu + ((u >> 16) & 1u)) >> 16;
}
__device__ __forceinline__ u32 pack2(float a, float b) {
  return f2bf(a) | (f2bf(b) << 16);
}

#define GLOAD16(g, l)                                                              \
  __builtin_amdgcn_global_load_lds((const __attribute__((address_space(1))) u32*)(g), \
                                   (__attribute__((address_space(3))) u32*)(l), 16, 0, 0)
#define VMCNT0 asm volatile("s_waitcnt vmcnt(0)" ::: "memory")

// ---------------- Stage 1: projections -> exp space -------------------------
__global__ __launch_bounds__(256) void kq_kernel(const float* __restrict__ rec,
                                                 const float* __restrict__ att,
                                                 const float* __restrict__ wq,
                                                 const float* __restrict__ wk,
                                                 const float* __restrict__ bias,
                                                 float* __restrict__ ekbuf,
                                                 float* __restrict__ eqbuf) {
  __shared__ float rr[512], ra[512];
  int tid = threadIdx.x;
  size_t base = (size_t)blockIdx.x * 8;
  const float* gr = rec + base * DD;
  const float* ga = att + base * DD;
  rr[tid] = gr[tid]; rr[tid + 256] = gr[tid + 256];
  ra[tid] = ga[tid]; ra[tid + 256] = ga[tid + 256];
  __syncthreads();
  int r = tid >> 5, h = tid & 31;
  float sk = bias[h], sq = 0.f;
  const float* rrow = &rr[r * DD];
  const float* arow = &ra[r * DD];
#pragma unroll 8
  for (int d = 0; d < DD; ++d) {
    sk += rrow[d] * wk[d * HH + h];
    sq += arow[d] * wq[d * HH + h];
  }
  const float C = 2.8853900817779268f;  // 2*log2(e)
  ekbuf[(base + r) * HH + h] = __builtin_exp2f(C * sk);
  eqbuf[(base + r) * HH + h] = __builtin_exp2f(C * sq);
}

// ------- Stage 2+3 fused: adj transpose/cast + e-scores (LDS union) ---------
// Per block (x=c/n-tile, y=r/m-tile, z=b):
//   phase A: adj[r0..][c0..] -> adjBF (bf16 row-major), t -> adjT (bf16 transposed)
//   phase B: Et[b][m0+m][n0+n] = asum - sum_h 2a_h/(eq[m]*ek[n]+1)
// Transpose traffic (memory-bound) hides under escore VALU (compute-bound).
__global__ __launch_bounds__(256) void prep_kernel(const float* __restrict__ adj,
                                                   const float* __restrict__ ek,
                                                   const float* __restrict__ eq,
                                                   const float* __restrict__ avec,
                                                   unsigned short* __restrict__ adjT,
                                                   unsigned short* __restrict__ adjBF,
                                                   unsigned short* __restrict__ Et) {
  __shared__ __align__(16) float smem[4608];           // union: t[64][65] | kl+ql
  float (*t)[65] = (float (*)[65])smem;
  float (*kl)[36] = (float (*)[36])smem;
  float (*ql)[36] = (float (*)[36])&smem[64 * 36];

  int tid = threadIdx.x;
  int b = blockIdx.z;
  int n0 = blockIdx.x * 64, m0 = blockIdx.y * 64;      // escore tile
  int c0 = n0, r0 = m0;                                 // transpose tile (bijection)

  // issue ek/eq tile loads early (land in regs; LDS-written in phase B)
  const float* kb = ek + ((size_t)b * GN + n0) * HH;
  const float* qb = eq + ((size_t)b * GN + m0) * HH;
  v4f rk[2], rq[2];
#pragma unroll
  for (int k = 0; k < 2; ++k) {
    int v = tid + k * 256;
    int row = v >> 3, seg = v & 7;
    rk[k] = *(const v4f*)(kb + row * HH + seg * 4);
    rq[k] = *(const v4f*)(qb + row * HH + seg * 4);
  }
  // wave-uniform a-vector constants
  v4f a2v[8];
  float asum = 0.f;
#pragma unroll
  for (int h4 = 0; h4 < 8; ++h4) {
    v4f av = *(const v4f*)(avec + h4 * 4);
    a2v[h4] = av * 2.0f;
    asum += av[0] + av[1] + av[2] + av[3];
  }

  // ---- phase A: transpose + bf16 cast ----
  const float* ab = adj + (size_t)b * GN * GN;
  unsigned short* ob = adjT + (size_t)b * GN * GN;
  unsigned short* of = adjBF + (size_t)b * GN * GN;
#pragma unroll
  for (int k = 0; k < 4; ++k) {
    int v = tid + k * 256;
    int row = v >> 4, seg = v & 15;
    v4f f = *(const v4f*)(ab + (size_t)(r0 + row) * GN + c0 + seg * 4);
    t[row][seg * 4 + 0] = f[0];
    t[row][seg * 4 + 1] = f[1];
    t[row][seg * 4 + 2] = f[2];
    t[row][seg * 4 + 3] = f[3];
    v2u p = {pack2(f[0], f[1]), pack2(f[2], f[3])};
    *(v2u*)(of + (size_t)(r0 + row) * GN + c0 + seg * 4) = p;
  }
  __syncthreads();
  {
    int c = tid >> 2;
    int rs = (tid & 3) * 16;
    v4u p0, p1;
#pragma unroll
    for (int j = 0; j < 4; ++j) {
      p0[j] = pack2(t[rs + 2 * j][c], t[rs + 2 * j + 1][c]);
      p1[j] = pack2(t[rs + 8 + 2 * j][c], t[rs + 9 + 2 * j][c]);
    }
    unsigned short* dst = ob + (size_t)(c0 + c) * GN + r0 + rs;
    *(v4u*)dst = p0;
    *(v4u*)(dst + 8) = p1;
  }
  __syncthreads();  // t reads done; safe to overwrite union with kl/ql

  // ---- phase B: escore ----
#pragma unroll
  for (int k = 0; k < 2; ++k) {
    int v = tid + k * 256;
    int row = v >> 3, seg = v & 7;
    *(v4f*)&kl[row][seg * 4] = rk[k];
    *(v4f*)&ql[row][seg * 4] = rq[k];
  }
  __syncthreads();
  int m = tid >> 2, ng = tid & 3;
  v4f qv[8];
#pragma unroll
  for (int h4 = 0; h4 < 8; ++h4) qv[h4] = *(const v4f*)&ql[m][h4 * 4];
  u32* dstw = (u32*)(Et + ((size_t)b * GN + m0 + m) * GN + n0);
#pragma unroll 2
  for (int nn = 0; nn < 8; ++nn) {
    int n = ng * 2 + nn * 8;
    v4f acc0 = (v4f){0.f, 0.f, 0.f, 0.f};
    v4f acc1 = (v4f){0.f, 0.f, 0.f, 0.f};
#pragma unroll
    for (int h4 = 0; h4 < 8; ++h4) {
      v4f kv0 = *(const v4f*)&kl[n][h4 * 4];
      v4f kv1 = *(const v4f*)&kl[n + 1][h4 * 4];
      v4f f0 = kv0 * qv[h4] + 1.0f;
      v4f f1 = kv1 * qv[h4] + 1.0f;
      v4f r0v, r1v;
#pragma unroll
      for (int e = 0; e < 4; ++e) {
        r0v[e] = __builtin_amdgcn_rcpf(f0[e]);
        r1v[e] = __builtin_amdgcn_rcpf(f1[e]);
      }
      acc0 += a2v[h4] * r0v;
      acc1 += a2v[h4] * r1v;
    }
    float s0 = asum - (acc0[0] + acc0[1] + acc0[2] + acc0[3]);
    float s1 = asum - (acc1[0] + acc1[1] + acc1[2] + acc1[3]);
    __bf16 b0 = (__bf16)s0, b1 = (__bf16)s1;
    u32 w = (u32)__builtin_bit_cast(unsigned short, b0) |
            ((u32)__builtin_bit_cast(unsigned short, b1) << 16);
    dstw[n >> 1] = w;
  }
}

// ---------------- Stage 4/5: batched bf16 GEMM, 2-phase pipelined -----------
#define SWZ(r, s) ((s) ^ ((r) & 7))

template <bool OUTF32>
__global__ __launch_bounds__(256) void gemm_bt(const unsigned short* __restrict__ A,
                                               const unsigned short* __restrict__ Bt,
                                               void* __restrict__ Cv) {
  __shared__ unsigned short At[2][128 * 64];  // 2 x 16 KiB
  __shared__ unsigned short Bs[2][128 * 64];
  int b = blockIdx.z;
  int row0 = blockIdx.y * 128, col0 = blockIdx.x * 128;
  int tid = threadIdx.x, lane = tid & 63, wave = tid >> 6;
  int wr = wave >> 1, wc = wave & 1;
  const unsigned short* Ab = A + (size_t)b * GN * GN;
  const unsigned short* Bb = Bt + (size_t)b * GN * GN;

  v4f acc[4][4];
#pragma unroll
  for (int i = 0; i < 4; ++i)
#pragma unroll
    for (int j = 0; j < 4; ++j) acc[i][j] = (v4f){0.f, 0.f, 0.f, 0.f};

  int cc_r[4], cc_s[4];
#pragma unroll
  for (int i = 0; i < 4; ++i) {
    int c = i * 256 + tid;
    cc_r[i] = c >> 3;
    cc_s[i] = SWZ(c >> 3, c & 7);
  }

#define STAGE(buf, kt)                                                                   \
  {                                                                                      \
    _Pragma("unroll") for (int i = 0; i < 4; ++i) {                                      \
      const unsigned short* ga = Ab + (size_t)(row0 + cc_r[i]) * GN + (kt)*64 + cc_s[i] * 8; \
      const unsigned short* gb = Bb + (size_t)(col0 + cc_r[i]) * GN + (kt)*64 + cc_s[i] * 8; \
      GLOAD16(ga, (char*)&At[buf][0] + (i * 256 + wave * 64) * 16);                      \
      GLOAD16(gb, (char*)&Bs[buf][0] + (i * 256 + wave * 64) * 16);                      \
    }                                                                                    \
  }

#define COMPUTE(buf)                                                                     \
  {                                                                                      \
    int lr = lane & 15, s16 = lane >> 4;                                                 \
    _Pragma("unroll") for (int h = 0; h < 2; ++h) {                                      \
      int sl = h * 4 + s16;                                                              \
      v8bf af[4], bfv[4];                                                                \
      _Pragma("unroll") for (int i = 0; i < 4; ++i) {                                    \
        int r = wr * 64 + i * 16 + lr;                                                   \
        af[i] = *(const v8bf*)&At[buf][r * 64 + SWZ(r, sl) * 8];                         \
      }                                                                                  \
      _Pragma("unroll") for (int j = 0; j < 4; ++j) {                                    \
        int r = wc * 64 + j * 16 + lr;                                                   \
        bfv[j] = *(const v8bf*)&Bs[buf][r * 64 + SWZ(r, sl) * 8];                        \
      }                                                                                  \
      _Pragma("unroll") for (int i = 0; i < 4; ++i)                                      \
          _Pragma("unroll") for (int j = 0; j < 4; ++j) acc[i][j] =                      \
          __builtin_amdgcn_mfma_f32_16x16x32_bf16(af[i], bfv[j], acc[i][j], 0, 0, 0);    \
    }                                                                                    \
  }

  STAGE(0, 0);
  VMCNT0;
  __builtin_amdgcn_s_barrier();
#pragma unroll
  for (int kt = 0; kt < 7; ++kt) {
    int cur = kt & 1;
    STAGE(cur ^ 1, kt + 1);
    COMPUTE(cur);
    VMCNT0;
    __builtin_amdgcn_s_barrier();
  }
  COMPUTE(1);

  int lc = lane & 15;
  int lrow4 = (lane >> 4) * 4;
#pragma unroll
  for (int i = 0; i < 4; ++i) {
#pragma unroll
    for (int j = 0; j < 4; ++j) {
      int gr = row0 + wr * 64 + i * 16 + lrow4;
      int gc = col0 + wc * 64 + j * 16 + lc;
#pragma unroll
      for (int e = 0; e < 4; ++e) {
        float v = acc[i][j][e];
        if constexpr (OUTF32)
          ((float*)Cv)[(size_t)b * GN * GN + (size_t)(gr + e) * GN + gc] = v;
        else
          ((unsigned short*)Cv)[(size_t)b * GN * GN + (size_t)(gr + e) * GN + gc] =
              (unsigned short)f2bf(v);
      }
    }
  }
#undef STAGE
#undef COMPUTE
}

// ---------------- launch ----------------------------------------------------
extern "C" void kernel_launch(void* const* d_in, const int* in_sizes, int n_in,
                              void* d_out, int out_size, void* d_ws, size_t ws_size,
                              hipStream_t stream) {
  const float* receiver  = (const float*)d_in[0];
  const float* attendant = (const float*)d_in[1];
  const float* adj       = (const float*)d_in[2];
  const float* wq        = (const float*)d_in[3];
  const float* wk        = (const float*)d_in[4];
  const float* bias      = (const float*)d_in[5];
  const float* avec      = (const float*)d_in[6];
  float* out = (float*)d_out;

  char* ws = (char*)d_ws;
  float* ekbuf          = (float*)(ws);                          // 2 MiB
  float* eqbuf          = (float*)(ws + (2u << 20));             // 2 MiB
  unsigned short* Et    = (unsigned short*)(ws + (4u << 20));    // 16 MiB
  unsigned short* adjT  = (unsigned short*)(ws + (20u << 20));   // 16 MiB
  unsigned short* adjBF = (unsigned short*)(ws + (36u << 20));   // 16 MiB
  unsigned short* Tbuf  = (unsigned short*)(ws + (52u << 20));   // 16 MiB

  kq_kernel<<<dim3(2048), dim3(256), 0, stream>>>(receiver, attendant, wq, wk, bias,
                                                  ekbuf, eqbuf);
  prep_kernel<<<dim3(8, 8, 32), dim3(256), 0, stream>>>(adj, ekbuf, eqbuf, avec,
                                                        adjT, adjBF, Et);
  // T = adjBF @ Et^T  -> bf16
  gemm_bt<false><<<dim3(4, 4, 32), dim3(256), 0, stream>>>(adjBF, Et, Tbuf);
  // out = Tbuf @ adjT^T -> f32
  gemm_bt<true><<<dim3(4, 4, 32), dim3(256), 0, stream>>>(Tbuf, adjT, out);
}

// Round 6
// 80.001 us; speedup vs baseline: 1.8118x; 1.1293x over previous
//
#include <hip/hip_runtime.h>

#define GN 512
#define HH 32
#define DD 64

typedef float v4f __attribute__((ext_vector_type(4)));
typedef unsigned int v4u __attribute__((ext_vector_type(4)));
typedef u_int32_t u32;
typedef u32 v2u __attribute__((ext_vector_type(2)));
typedef __bf16 v8bf __attribute__((ext_vector_type(8)));

__device__ __forceinline__ u32 f2bf(float f) {
  u32 u = __builtin_bit_cast(u32, f);
  return (u + 0x7fffu + ((u >> 16) & 1u)) >> 16;
}
__device__ __forceinline__ u32 pack2(float a, float b) {
  return f2bf(a) | (f2bf(b) << 16);
}

#define GLOAD16(g, l)                                                              \
  __builtin_amdgcn_global_load_lds((const __attribute__((address_space(1))) u32*)(g), \
                                   (__attribute__((address_space(3))) u32*)(l), 16, 0, 0)
#define VMCNT0 asm volatile("s_waitcnt vmcnt(0)" ::: "memory")

// ---------------- Stage 1: projections -> exp space -------------------------
__global__ __launch_bounds__(256) void kq_kernel(const float* __restrict__ rec,
                                                 const float* __restrict__ att,
                                                 const float* __restrict__ wq,
                                                 const float* __restrict__ wk,
                                                 const float* __restrict__ bias,
                                                 float* __restrict__ ekbuf,
                                                 float* __restrict__ eqbuf) {
  __shared__ float rr[512], ra[512];
  int tid = threadIdx.x;
  size_t base = (size_t)blockIdx.x * 8;
  const float* gr = rec + base * DD;
  const float* ga = att + base * DD;
  rr[tid] = gr[tid]; rr[tid + 256] = gr[tid + 256];
  ra[tid] = ga[tid]; ra[tid + 256] = ga[tid + 256];
  __syncthreads();
  int r = tid >> 5, h = tid & 31;
  float sk = bias[h], sq = 0.f;
  const float* rrow = &rr[r * DD];
  const float* arow = &ra[r * DD];
#pragma unroll 8
  for (int d = 0; d < DD; ++d) {
    sk += rrow[d] * wk[d * HH + h];
    sq += arow[d] * wq[d * HH + h];
  }
  const float C = 2.8853900817779268f;  // 2*log2(e)
  ekbuf[(base + r) * HH + h] = __builtin_exp2f(C * sk);
  eqbuf[(base + r) * HH + h] = __builtin_exp2f(C * sq);
}

// ------- Stage 2+3 fused: adj transpose/cast + e-scores (LDS union) ---------
__global__ __launch_bounds__(256) void prep_kernel(const float* __restrict__ adj,
                                                   const float* __restrict__ ek,
                                                   const float* __restrict__ eq,
                                                   const float* __restrict__ avec,
                                                   unsigned short* __restrict__ adjT,
                                                   unsigned short* __restrict__ adjBF,
                                                   unsigned short* __restrict__ Et) {
  __shared__ __align__(16) float smem[4608];           // union: t[64][65] | kl+ql
  float (*t)[65] = (float (*)[65])smem;
  float (*kl)[36] = (float (*)[36])smem;
  float (*ql)[36] = (float (*)[36])&smem[64 * 36];

  int tid = threadIdx.x;
  int b = blockIdx.z;
  int n0 = blockIdx.x * 64, m0 = blockIdx.y * 64;      // escore tile
  int c0 = n0, r0 = m0;                                 // transpose tile (bijection)

  const float* kb = ek + ((size_t)b * GN + n0) * HH;
  const float* qb = eq + ((size_t)b * GN + m0) * HH;
  v4f rk[2], rq[2];
#pragma unroll
  for (int k = 0; k < 2; ++k) {
    int v = tid + k * 256;
    int row = v >> 3, seg = v & 7;
    rk[k] = *(const v4f*)(kb + row * HH + seg * 4);
    rq[k] = *(const v4f*)(qb + row * HH + seg * 4);
  }
  v4f a2v[8];
  float asum = 0.f;
#pragma unroll
  for (int h4 = 0; h4 < 8; ++h4) {
    v4f av = *(const v4f*)(avec + h4 * 4);
    a2v[h4] = av * 2.0f;
    asum += av[0] + av[1] + av[2] + av[3];
  }

  // ---- phase A: transpose + bf16 cast ----
  const float* ab = adj + (size_t)b * GN * GN;
  unsigned short* ob = adjT + (size_t)b * GN * GN;
  unsigned short* of = adjBF + (size_t)b * GN * GN;
#pragma unroll
  for (int k = 0; k < 4; ++k) {
    int v = tid + k * 256;
    int row = v >> 4, seg = v & 15;
    v4f f = *(const v4f*)(ab + (size_t)(r0 + row) * GN + c0 + seg * 4);
    t[row][seg * 4 + 0] = f[0];
    t[row][seg * 4 + 1] = f[1];
    t[row][seg * 4 + 2] = f[2];
    t[row][seg * 4 + 3] = f[3];
    v2u p = {pack2(f[0], f[1]), pack2(f[2], f[3])};
    *(v2u*)(of + (size_t)(r0 + row) * GN + c0 + seg * 4) = p;
  }
  __syncthreads();
  {
    int c = tid >> 2;
    int rs = (tid & 3) * 16;
    v4u p0, p1;
#pragma unroll
    for (int j = 0; j < 4; ++j) {
      p0[j] = pack2(t[rs + 2 * j][c], t[rs + 2 * j + 1][c]);
      p1[j] = pack2(t[rs + 8 + 2 * j][c], t[rs + 9 + 2 * j][c]);
    }
    unsigned short* dst = ob + (size_t)(c0 + c) * GN + r0 + rs;
    *(v4u*)dst = p0;
    *(v4u*)(dst + 8) = p1;
  }
  __syncthreads();  // t reads done; safe to overwrite union with kl/ql

  // ---- phase B: escore ----
#pragma unroll
  for (int k = 0; k < 2; ++k) {
    int v = tid + k * 256;
    int row = v >> 3, seg = v & 7;
    *(v4f*)&kl[row][seg * 4] = rk[k];
    *(v4f*)&ql[row][seg * 4] = rq[k];
  }
  __syncthreads();
  int m = tid >> 2, ng = tid & 3;
  v4f qv[8];
#pragma unroll
  for (int h4 = 0; h4 < 8; ++h4) qv[h4] = *(const v4f*)&ql[m][h4 * 4];
  u32* dstw = (u32*)(Et + ((size_t)b * GN + m0 + m) * GN + n0);
#pragma unroll 4
  for (int nn = 0; nn < 8; ++nn) {
    int n = ng * 2 + nn * 8;
    v4f acc0 = (v4f){0.f, 0.f, 0.f, 0.f};
    v4f acc1 = (v4f){0.f, 0.f, 0.f, 0.f};
#pragma unroll
    for (int h4 = 0; h4 < 8; ++h4) {
      v4f kv0 = *(const v4f*)&kl[n][h4 * 4];
      v4f kv1 = *(const v4f*)&kl[n + 1][h4 * 4];
      v4f f0 = kv0 * qv[h4] + 1.0f;
      v4f f1 = kv1 * qv[h4] + 1.0f;
      v4f r0v, r1v;
#pragma unroll
      for (int e = 0; e < 4; ++e) {
        r0v[e] = __builtin_amdgcn_rcpf(f0[e]);
        r1v[e] = __builtin_amdgcn_rcpf(f1[e]);
      }
      acc0 += a2v[h4] * r0v;
      acc1 += a2v[h4] * r1v;
    }
    float s0 = asum - (acc0[0] + acc0[1] + acc0[2] + acc0[3]);
    float s1 = asum - (acc1[0] + acc1[1] + acc1[2] + acc1[3]);
    __bf16 b0 = (__bf16)s0, b1 = (__bf16)s1;
    u32 w = (u32)__builtin_bit_cast(unsigned short, b0) |
            ((u32)__builtin_bit_cast(unsigned short, b1) << 16);
    dstw[n >> 1] = w;
  }
}

// ---------------- Stage 4/5: batched bf16 GEMM, 2-phase + XCD swizzle -------
// 1D grid of 512 blocks; bijective XCD swizzle (512 % 8 == 0) maps 64
// consecutive tiles = 4 complete batches (4 MB of A+B panels = one L2) per XCD.
#define SWZ(r, s) ((s) ^ ((r) & 7))

template <bool OUTF32>
__global__ __launch_bounds__(256) void gemm_bt(const unsigned short* __restrict__ A,
                                               const unsigned short* __restrict__ Bt,
                                               void* __restrict__ Cv) {
  __shared__ unsigned short At[2][128 * 64];  // 2 x 16 KiB
  __shared__ unsigned short Bs[2][128 * 64];
  int bid = blockIdx.x;
  int swz = (bid & 7) * 64 + (bid >> 3);      // XCD-chunked, bijective
  int b = swz >> 4;
  int row0 = ((swz >> 2) & 3) * 128;
  int col0 = (swz & 3) * 128;
  int tid = threadIdx.x, lane = tid & 63, wave = tid >> 6;
  int wr = wave >> 1, wc = wave & 1;
  const unsigned short* Ab = A + (size_t)b * GN * GN;
  const unsigned short* Bb = Bt + (size_t)b * GN * GN;

  v4f acc[4][4];
#pragma unroll
  for (int i = 0; i < 4; ++i)
#pragma unroll
    for (int j = 0; j < 4; ++j) acc[i][j] = (v4f){0.f, 0.f, 0.f, 0.f};

  int cc_r[4], cc_s[4];
#pragma unroll
  for (int i = 0; i < 4; ++i) {
    int c = i * 256 + tid;
    cc_r[i] = c >> 3;
    cc_s[i] = SWZ(c >> 3, c & 7);
  }

#define STAGE(buf, kt)                                                                   \
  {                                                                                      \
    _Pragma("unroll") for (int i = 0; i < 4; ++i) {                                      \
      const unsigned short* ga = Ab + (size_t)(row0 + cc_r[i]) * GN + (kt)*64 + cc_s[i] * 8; \
      const unsigned short* gb = Bb + (size_t)(col0 + cc_r[i]) * GN + (kt)*64 + cc_s[i] * 8; \
      GLOAD16(ga, (char*)&At[buf][0] + (i * 256 + wave * 64) * 16);                      \
      GLOAD16(gb, (char*)&Bs[buf][0] + (i * 256 + wave * 64) * 16);                      \
    }                                                                                    \
  }

#define COMPUTE(buf)                                                                     \
  {                                                                                      \
    int lr = lane & 15, s16 = lane >> 4;                                                 \
    _Pragma("unroll") for (int h = 0; h < 2; ++h) {                                      \
      int sl = h * 4 + s16;                                                              \
      v8bf af[4], bfv[4];                                                                \
      _Pragma("unroll") for (int i = 0; i < 4; ++i) {                                    \
        int r = wr * 64 + i * 16 + lr;                                                   \
        af[i] = *(const v8bf*)&At[buf][r * 64 + SWZ(r, sl) * 8];                         \
      }                                                                                  \
      _Pragma("unroll") for (int j = 0; j < 4; ++j) {                                    \
        int r = wc * 64 + j * 16 + lr;                                                   \
        bfv[j] = *(const v8bf*)&Bs[buf][r * 64 + SWZ(r, sl) * 8];                        \
      }                                                                                  \
      _Pragma("unroll") for (int i = 0; i < 4; ++i)                                      \
          _Pragma("unroll") for (int j = 0; j < 4; ++j) acc[i][j] =                      \
          __builtin_amdgcn_mfma_f32_16x16x32_bf16(af[i], bfv[j], acc[i][j], 0, 0, 0);    \
    }                                                                                    \
  }

  STAGE(0, 0);
  VMCNT0;
  __builtin_amdgcn_s_barrier();
#pragma unroll
  for (int kt = 0; kt < 7; ++kt) {
    int cur = kt & 1;
    STAGE(cur ^ 1, kt + 1);
    COMPUTE(cur);
    VMCNT0;
    __builtin_amdgcn_s_barrier();
  }
  COMPUTE(1);

  int lc = lane & 15;
  int lrow4 = (lane >> 4) * 4;
#pragma unroll
  for (int i = 0; i < 4; ++i) {
#pragma unroll
    for (int j = 0; j < 4; ++j) {
      int gr = row0 + wr * 64 + i * 16 + lrow4;
      int gc = col0 + wc * 64 + j * 16 + lc;
#pragma unroll
      for (int e = 0; e < 4; ++e) {
        float v = acc[i][j][e];
        if constexpr (OUTF32)
          ((float*)Cv)[(size_t)b * GN * GN + (size_t)(gr + e) * GN + gc] = v;
        else
          ((unsigned short*)Cv)[(size_t)b * GN * GN + (size_t)(gr + e) * GN + gc] =
              (unsigned short)f2bf(v);
      }
    }
  }
#undef STAGE
#undef COMPUTE
}

// ---------------- launch ----------------------------------------------------
extern "C" void kernel_launch(void* const* d_in, const int* in_sizes, int n_in,
                              void* d_out, int out_size, void* d_ws, size_t ws_size,
                              hipStream_t stream) {
  const float* receiver  = (const float*)d_in[0];
  const float* attendant = (const float*)d_in[1];
  const float* adj       = (const float*)d_in[2];
  const float* wq        = (const float*)d_in[3];
  const float* wk        = (const float*)d_in[4];
  const float* bias      = (const float*)d_in[5];
  const float* avec      = (const float*)d_in[6];
  float* out = (float*)d_out;

  char* ws = (char*)d_ws;
  float* ekbuf          = (float*)(ws);                          // 2 MiB
  float* eqbuf          = (float*)(ws + (2u << 20));             // 2 MiB
  unsigned short* Et    = (unsigned short*)(ws + (4u << 20));    // 16 MiB
  unsigned short* adjT  = (unsigned short*)(ws + (20u << 20));   // 16 MiB
  unsigned short* adjBF = (unsigned short*)(ws + (36u << 20));   // 16 MiB
  unsigned short* Tbuf  = (unsigned short*)(ws + (52u << 20));   // 16 MiB

  kq_kernel<<<dim3(2048), dim3(256), 0, stream>>>(receiver, attendant, wq, wk, bias,
                                                  ekbuf, eqbuf);
  prep_kernel<<<dim3(8, 8, 32), dim3(256), 0, stream>>>(adj, ekbuf, eqbuf, avec,
                                                        adjT, adjBF, Et);
  // T = adjBF @ Et^T  -> bf16
  gemm_bt<false><<<dim3(512), dim3(256), 0, stream>>>(adjBF, Et, Tbuf);
  // out = Tbuf @ adjT^T -> f32
  gemm_bt<true><<<dim3(512), dim3(256), 0, stream>>>(Tbuf, adjT, out);
}